// Round 6
// baseline (244.960 us; speedup 1.0000x reference)
//
#include <hip/hip_runtime.h>
#include <hip/hip_bf16.h>
#include <stdint.h>

// Cheb graph conv: out[b,o,m,t] = sum_{k,n,c} T_k[n,m] x[b,c,n,t] Theta[k,c,o]
// Folded:  W[(o,m)][(c,n)] = sum_k T_k[n,m] Theta[k,c,o]
//          out_b (768x512) = W @ x_b (768x512) per batch, bf16 MFMA.
// R11 = R10 with the stage PIPELINED into the main loop (R10 measured 105us:
// 1 block/CU => stage/main/epilogue phases fully serialized; MfmaUtil 14%).
//  - Bs chunk kc (k-units kc*24..+23) feeds exactly kt = 6kc..6kc+5. Per kc:
//    {write LSf from regs; sync; cvt->Bs(kc); issue x-loads(kc+1); sync;
//     6 kt of MFMA}. x HBM latency + transpose hide under ~5600cy of MFMA.
//  - plain cached stores (R10's nontemporal evicted half-lines: WRITE_SIZE
//    142MB vs 101MB out => 1.42x amplification), j-innermost for line combine.
//  - float4 stage loads; FSTR 66->68 for 16B-aligned LDS float4 writes
//    (8 lanes per 16B-unit residue => b128 conflict-free).
// LDS: Bs 96KB (bf16 [64t][96ku] XOR-swizzled) + LSf 52.2KB fp32 staging.

#define NV 24
#define CIN 32
#define COUT 32
#define TDIM 512
#define BATCH 64
#define MDIM 768   // COUT*NV
#define KD 768     // CIN*NV
#define BK 32
#define NKT (KD / BK)    // 24
#define BM 128           // Wp blob row-block (packing unchanged)
#define BLOB (BM * BK)   // 4096 shorts = 8 KB per (mtq,kt) A blob
#define BT 64            // t-cols per block
#define KUN (KD / 8)     // 96 k-units of 8 bf16
#define FSTR 68          // fp32 staging row stride (64 + 4 pad, 16B-aligned)

typedef __attribute__((ext_vector_type(8))) short short8v;  // 8 bf16
typedef __attribute__((ext_vector_type(4))) float float4v;  // 4 fp32 acc

__device__ inline unsigned short f2bf(float f) {
    unsigned int u = __float_as_uint(f);
    unsigned int r = (u + 0x7fffu + ((u >> 16) & 1u)) >> 16;
    return (unsigned short)r;
}

// ---------------------------------------------------------------------------
// prep_w: 64 blocks x 256 thr; writes Wp packed [mtq][kt][128 m][32 k] bf16.
__global__ __launch_bounds__(256) void prep_w(const float* __restrict__ adj,
                                              const float* __restrict__ Theta,
                                              unsigned short* __restrict__ Wp) {
    __shared__ float adjS[NV * NV];
    __shared__ float disS[NV];
    __shared__ float LS[NV * NV];
    __shared__ float T2S[NV * NV];
    int tid = threadIdx.x;
    for (int e = tid; e < NV * NV; e += 256) adjS[e] = adj[e];
    __syncthreads();
    if (tid < NV) {
        float d = 0.f;
        for (int j = 0; j < NV; ++j) d += adjS[tid * NV + j];
        disS[tid] = (d > 0.f) ? rsqrtf(d) : 0.f;
    }
    __syncthreads();
    for (int e = tid; e < NV * NV; e += 256) {
        int i = e / NV, j = e % NV;
        LS[e] = disS[i] * adjS[j * NV + i] * disS[j];  // L = D^-1/2 A^T D^-1/2
    }
    __syncthreads();
    for (int e = tid; e < NV * NV; e += 256) {
        int i = e / NV, j = e % NV;
        float s = 0.f;
        for (int p = 0; p < NV; ++p) s += LS[i * NV + p] * LS[p * NV + j];
        T2S[e] = 2.f * s - (i == j ? 1.f : 0.f);
    }
    __syncthreads();
    int r0 = blockIdx.x * (MDIM / 64);  // 12 rows per block
    for (int e = tid; e < (MDIM / 64) * KD; e += 256) {
        int lr = e / KD, col = e % KD;
        int row = r0 + lr;
        int o = row / NV, m = row % NV;
        int c = col / NV, n = col % NV;
        float th0 = Theta[0 * CIN * COUT + c * COUT + o];
        float th1 = Theta[1 * CIN * COUT + c * COUT + o];
        float th2 = Theta[2 * CIN * COUT + c * COUT + o];
        float v = (n == m ? th0 : 0.f) + LS[n * NV + m] * th1 + T2S[n * NV + m] * th2;
        size_t idx = (((size_t)(row >> 7) * NKT + (col >> 5)) * BM + (row & 127)) * BK + (col & 31);
        Wp[idx] = f2bf(v);
    }
}

// ---------------------------------------------------------------------------
// One kt step of the main loop. AC holds A fragments for KT; AN receives KT+1.
// Register-array indices are all compile-time (rule #20); KT may be runtime.
#define GSTEP(KT, AC, AN)                                                      \
    do {                                                                       \
        int kx = (((KT) * 4 + quad) ^ s7);                                     \
        short8v bb[4];                                                         \
        _Pragma("unroll")                                                      \
        for (int j = 0; j < 4; ++j) bb[j] = Bsv[tj[j] + kx];                   \
        if ((KT) + 1 < NKT) {                                                  \
            _Pragma("unroll")                                                  \
            for (int i = 0; i < 6; ++i) AN[i] = Apv[aoff[i] + ((KT) + 1) * 512]; \
        }                                                                      \
        _Pragma("unroll")                                                      \
        for (int i = 0; i < 6; ++i)                                            \
            _Pragma("unroll")                                                  \
            for (int j = 0; j < 4; ++j)                                        \
                acc[i][j] = __builtin_amdgcn_mfma_f32_16x16x32_bf16(           \
                    AC[i], bb[j], acc[i][j], 0, 0, 0);                         \
    } while (0)

// issue chunk KC's x-loads into vx (192 rows x 16 float4 = 3072 = 512thr x 6)
#define LOADC(KC)                                                              \
    _Pragma("unroll")                                                          \
    for (int p = 0; p < 6; ++p) {                                              \
        int idx = p * 512 + tid;                                               \
        int kloc = idx >> 4, c4 = idx & 15;                                    \
        vx[p] = *(const float4*)(xg + (size_t)((KC) * 192 + kloc) * TDIM + c4 * 4); \
    }

// gemm_fullm: grid 512 = 64 b x 8 tt. 512 thr = 8 waves; wave w owns rows
// [w*96, w*96+96) x all 64 t. out tile per block = 768m x 64t.
__global__ __launch_bounds__(512, 2) void gemm_fullm(const unsigned short* __restrict__ Wp,
                                                     const float* __restrict__ x,
                                                     float* __restrict__ out) {
    // Bs: bf16 [t=64][ku=96] 16B units, XOR-swizzled (unit ^= t&7) -> 96 KB.
    __shared__ __attribute__((aligned(16))) unsigned short Bs[BT * KUN * 8];
    // LSf: fp32 transpose staging, one 192k x 64t chunk -> 52.2 KB.
    __shared__ __attribute__((aligned(16))) float LSf[192 * FSTR];

    int id = blockIdx.x;
    int b = id >> 3;
    int tt = id & 7;
    int tid = threadIdx.x;
    int w = tid >> 6;          // wave 0..7
    int lane = tid & 63;
    int quad = lane >> 4;
    int l16 = lane & 15;
    int t = lane;              // stage phase-B: this thread's t column
    int s7 = l16 & 7;          // read-side swizzle key (t_j & 7 == l16 & 7)

    const float* xg = x + (size_t)b * KD * TDIM + (size_t)tt * BT;
    short8v* Bsv = (short8v*)Bs;

    // ---- A fragment global offsets (16B units into Wp) ----
    const short8v* Apv = (const short8v*)Wp;
    int aoff[6];
#pragma unroll
    for (int i = 0; i < 6; ++i) {
        int r = w * 96 + i * 16 + l16;
        aoff[i] = (r >> 7) * (NKT * 512) + (r & 127) * 4 + quad;
    }
    int tj[4];
#pragma unroll
    for (int j = 0; j < 4; ++j) tj[j] = (j * 16 + l16) * KUN;

    const float4v zero4 = {0.f, 0.f, 0.f, 0.f};
    float4v acc[6][4];
#pragma unroll
    for (int i = 0; i < 6; ++i)
#pragma unroll
        for (int j = 0; j < 4; ++j) acc[i][j] = zero4;

    // ---- prologue: x chunk 0 + A(kt=0) in flight ----
    float4 vx[6];
    LOADC(0);
    short8v Aev[6], Aod[6];
#pragma unroll
    for (int i = 0; i < 6; ++i) Aev[i] = Apv[aoff[i]];  // kt = 0

    // ---- pipelined chunks: stage(kc) hides under MFMA of chunk kc-1..kc ----
    for (int kc = 0; kc < 4; ++kc) {
        // write staged fp32 chunk to LSf (waits only on vx loads)
#pragma unroll
        for (int p = 0; p < 6; ++p) {
            int idx = p * 512 + tid;
            int kloc = idx >> 4, c4 = idx & 15;
            *(float4*)(&LSf[kloc * FSTR + c4 * 4]) = vx[p];
        }
        __syncthreads();  // LSf chunk kc visible (and prior phase-B reads done)
        // phase B: cvt fp32 -> bf16, write Bs k-units kc*24 + w*3 + c
#pragma unroll
        for (int c = 0; c < 3; ++c) {
            union { short8v s; __hip_bfloat162 h[4]; } u;
#pragma unroll
            for (int p = 0; p < 4; ++p) {
                float f0 = LSf[(w * 24 + c * 8 + 2 * p) * FSTR + t];
                float f1 = LSf[(w * 24 + c * 8 + 2 * p + 1) * FSTR + t];
                u.h[p] = __float22bfloat162_rn({f0, f1});
            }
            int ku = kc * 24 + w * 3 + c;
            Bsv[t * KUN + (ku ^ (t & 7))] = u.s;
        }
        // issue next chunk's x-loads; they stay in flight across the barrier
        // and complete under the 6-kt MFMA section below.
        if (kc + 1 < 4) { LOADC(kc + 1); }
        __syncthreads();  // Bs chunk kc ready; LSf reads drained

        // 6 kt of MFMA on chunk kc; A fragments reg-double-buffered.
        int k0 = kc * 6;
        GSTEP(k0 + 0, Aev, Aod);
        GSTEP(k0 + 1, Aod, Aev);
        GSTEP(k0 + 2, Aev, Aod);
        GSTEP(k0 + 3, Aod, Aev);
        GSTEP(k0 + 4, Aev, Aod);
        GSTEP(k0 + 5, Aod, Aev);
    }

    // ---- epilogue: C/D layout (m89): col = l16, row = quad*4 + reg ----
    // Plain cached stores (L2 write-combines full 128B lines), j innermost so
    // each row's 256B span completes across 4 consecutive stores.
    float* outB = out + (size_t)b * MDIM * TDIM + (size_t)tt * BT;
    int rb0 = w * 96;
#pragma unroll
    for (int i = 0; i < 6; ++i) {
#pragma unroll
        for (int r = 0; r < 4; ++r) {
            int row = rb0 + i * 16 + quad * 4 + r;
#pragma unroll
            for (int j = 0; j < 4; ++j) {
                int col = j * 16 + l16;
                outB[(size_t)row * TDIM + col] = acc[i][j][r];
            }
        }
    }
}

// ---------------------------------------------------------------------------
extern "C" void kernel_launch(void* const* d_in, const int* in_sizes, int n_in,
                              void* d_out, int out_size, void* d_ws, size_t ws_size,
                              hipStream_t stream) {
    const float* x = (const float*)d_in[0];      // (64,32,24,512) fp32
    const float* adj = (const float*)d_in[1];    // (24,24) fp32
    const float* Theta = (const float*)d_in[2];  // (3,32,32) fp32
    float* out = (float*)d_out;                  // (64,32,24,512) fp32

    unsigned short* Wp = (unsigned short*)d_ws;  // 1.125 MB packed W

    prep_w<<<64, 256, 0, stream>>>(adj, Theta, Wp);
    gemm_fullm<<<BATCH * (TDIM / BT), 512, 0, stream>>>(Wp, x, out);
}